// Round 6
// baseline (285.562 us; speedup 1.0000x reference)
//
#include <hip/hip_runtime.h>
#include <math.h>

// Problem geometry (fixed by the reference): B=32, C=16, H=W=256.
#define HW4 16384          // float4 groups per channel-plane
#define CTOT 16
#define NPIX (32 * 65536)  // pixels per channel

// Accumulator slots in workspace (double[22]):
//  0.. 2 : ch15 line_seg  (sumPosLoss, sumNegLoss, cntPos)
//  3.. 5 : ch14 junc_seg
//  6.. 8 : ch0  sol_center
//  9..11 : ch7  tp_center
// 12..13 : sol disp (sumMinLoss, cntPos)
// 14..15 : tp  disp
// 16..18 : sol len/angle (sumLen, sumAngle, cntPos)
// 19..21 : tp  len/angle
#define NACC 22

// 2048 blocks x 256 threads; block covers batch b = blk>>6, 256 consecutive
// float4 columns, ALL 32 plane-slices staged to LDS in two 16-slot rounds via
// global_load_lds (zero-VGPR async DMA -> deep MLP the compiler can't defeat).
#define GRID_BLOCKS 2048

__device__ __forceinline__ float smooth_l1(float p, float g) {
    float d = fabsf(p - g);
    return (d < 1.0f) ? 0.5f * d * d : d - 0.5f;
}
// a=|x| >= 0 so 1+exp(-a) in (1,2]: plain __logf is safe (abs err < 6e-8).
__device__ __forceinline__ float bce_logits(float x, float t) {
    float e = __expf(-fabsf(x));
    return fmaxf(x, 0.0f) - x * t + __logf(1.0f + e);
}
__device__ __forceinline__ float sigmoid_fast(float x) {
    return __builtin_amdgcn_rcpf(1.0f + __expf(-x));
}
__device__ __forceinline__ float get4(const float4& v, int j) {
    return j == 0 ? v.x : (j == 1 ? v.y : (j == 2 ? v.z : v.w));
}

// Async global->LDS, 16 B per lane. LDS dest is wave-uniform base + lane*16;
// gsrc is per-lane (lane i reads gsrc + i, a contiguous 1 KB burst).
__device__ __forceinline__ void async_ld16(const float4* gsrc, float4* ldst) {
    __builtin_amdgcn_global_load_lds(
        (const __attribute__((address_space(1))) void*)gsrc,
        (__attribute__((address_space(3))) void*)ldst,
        16, 0, 0);
}

__global__ __launch_bounds__(256) void loss_kernel(const float* __restrict__ preds,
                                                   const float* __restrict__ gts,
                                                   double* __restrict__ ws) {
    // 4 waves x 16 slots x 64 lanes x 16 B = 64 KB (2 blocks/CU resident).
    __shared__ float4 lds[4][16][64];

    const float4* pf = (const float4*)preds;
    const float4* gf = (const float4*)gts;
    const int w    = threadIdx.x >> 6;
    const int lane = threadIdx.x & 63;
    const int b    = blockIdx.x >> 6;                       // 0..31 batch
    const int col  = ((blockIdx.x & 63) << 8) + (w << 6);   // wave's hw4 base
    // lane i's element of plane ch: pf[(b*16+ch)*HW4 + col + lane]
    const size_t base = ((size_t)b * CTOT) * HW4 + col + lane;

    float acc[NACC];
#pragma unroll
    for (int i = 0; i < NACC; ++i) acc[i] = 0.0f;

    // ================= Round A: displacement (16 plane-slices) =================
    // slots 0-3: pred ch1-4 | 4-7: gt ch1-4 | 8-11: pred ch8-11 | 12-15: gt ch8-11
    {
        const int chs[8] = {1, 2, 3, 4, 8, 9, 10, 11};
#pragma unroll
        for (int k = 0; k < 8; ++k) {
            const int s = (k < 4) ? k : (4 + k);            // 0-3, 8-11
            const size_t off = base + (size_t)chs[k] * HW4;
            async_ld16(pf + off, &lds[w][s][0]);
            async_ld16(gf + off, &lds[w][s + 4][0]);
        }
    }
    __syncthreads();   // drains vmcnt(0): all 64 staged KB have landed

#pragma unroll
    for (int grp = 0; grp < 2; ++grp) {
        const int s0 = grp * 8;
        const int bs = 12 + grp * 2;
        float4 P0 = lds[w][s0 + 0][lane], P1 = lds[w][s0 + 1][lane];
        float4 P2 = lds[w][s0 + 2][lane], P3 = lds[w][s0 + 3][lane];
        float4 G0 = lds[w][s0 + 4][lane], G1 = lds[w][s0 + 5][lane];
        float4 G2 = lds[w][s0 + 6][lane], G3 = lds[w][s0 + 7][lane];
#pragma unroll
        for (int j = 0; j < 4; ++j) {
            float a0 = get4(P0, j), a1 = get4(P1, j), a2 = get4(P2, j), a3 = get4(P3, j);
            float b0 = get4(G0, j), b1 = get4(G1, j), b2 = get4(G2, j), b3 = get4(G3, j);
            float posv = fabsf(b0) + fabsf(b1) + fabsf(b2) + fabsf(b3);
            float m = (posv != 0.0f) ? 1.0f : 0.0f;
            float l1 = smooth_l1(a0, b0) + smooth_l1(a1, b1) +
                       smooth_l1(a2, b2) + smooth_l1(a3, b3);
            // swap = concat(pred[2:], pred[:2]) -> [p2,p3,p0,p1] vs gt
            float l2 = smooth_l1(a2, b0) + smooth_l1(a3, b1) +
                       smooth_l1(a0, b2) + smooth_l1(a1, b3);
            acc[bs + 0] += fminf(l1, l2) * m;
            acc[bs + 1] += m;
        }
    }
    __syncthreads();   // all reads of round-A LDS done before round B overwrites

    // ============ Round B: BCE (8 slices) + len/angle (8 slices) ============
    // slots 0-3: pred ch{15,14,0,7} | 4-7: gt ch{15,14,0,7}
    // slots 8: p5  9: p6  10: g5  11: g6 | 12: p12  13: p13  14: g12  15: g13
    {
        const int bch[4] = {15, 14, 0, 7};
#pragma unroll
        for (int k = 0; k < 4; ++k) {
            const size_t off = base + (size_t)bch[k] * HW4;
            async_ld16(pf + off, &lds[w][k][0]);
            async_ld16(gf + off, &lds[w][k + 4][0]);
        }
        const int lch[4] = {5, 6, 12, 13};
#pragma unroll
        for (int k = 0; k < 4; ++k) {
            const size_t off = base + (size_t)lch[k] * HW4;
            const int s = (k < 2) ? (8 + k) : (10 + k);     // p: 8,9,12,13
            async_ld16(pf + off, &lds[w][s][0]);
            async_ld16(gf + off, &lds[w][s + 2][0]);        // g: 10,11,14,15
        }
    }
    __syncthreads();

    // BCE: 4 channels -> acc bases {0,3,6,9}
    {
        const int bases[4] = {0, 3, 6, 9};
#pragma unroll
        for (int k = 0; k < 4; ++k) {
            float4 p = lds[w][k][lane];
            float4 t = lds[w][k + 4][lane];
            const int bs = bases[k];
#pragma unroll
            for (int j = 0; j < 4; ++j) {
                float x  = get4(p, j);
                float tv = get4(t, j);
                float loss = bce_logits(x, tv);
                float pos  = (tv != 0.0f) ? 1.0f : 0.0f;
                acc[bs + 0] += loss * pos;
                acc[bs + 1] += loss * (1.0f - pos);
                acc[bs + 2] += pos;
            }
        }
    }
    // len/angle: sol (slots 8-11) -> acc 16..18, tp (slots 12-15) -> acc 19..21
#pragma unroll
    for (int k = 0; k < 2; ++k) {
        float4 pl = lds[w][8 + 4 * k + 0][lane];
        float4 pa = lds[w][8 + 4 * k + 1][lane];
        float4 gl = lds[w][8 + 4 * k + 2][lane];
        float4 ga = lds[w][8 + 4 * k + 3][lane];
        const int bs = 16 + 3 * k;
#pragma unroll
        for (int j = 0; j < 4; ++j) {
            float glv = get4(gl, j);
            float m = (glv != 0.0f) ? 1.0f : 0.0f;
            acc[bs + 0] += smooth_l1(sigmoid_fast(get4(pl, j)), glv) * m;
            acc[bs + 1] += smooth_l1(sigmoid_fast(get4(pa, j)), get4(ga, j)) * m;
            acc[bs + 2] += m;
        }
    }

    // ---- wave (64-lane) butterfly reduce each accumulator ----
#pragma unroll
    for (int i = 0; i < NACC; ++i) {
        float v = acc[i];
#pragma unroll
        for (int off = 32; off > 0; off >>= 1) v += __shfl_down(v, off, 64);
        acc[i] = v;
    }

    // cross-wave reduce: reuse staging LDS (all reads above are complete)
    __syncthreads();
    float* red = (float*)&lds[0][0][0];   // red[wave*NACC + i]
    if (lane == 0) {
#pragma unroll
        for (int i = 0; i < NACC; ++i) red[w * NACC + i] = acc[i];
    }
    __syncthreads();
    if (threadIdx.x < NACC) {
        float s = red[0 * NACC + threadIdx.x] + red[1 * NACC + threadIdx.x] +
                  red[2 * NACC + threadIdx.x] + red[3 * NACC + threadIdx.x];
        atomicAdd(&ws[threadIdx.x], (double)s);
    }
}

__global__ void finalize_kernel(const double* __restrict__ ws, float* __restrict__ out) {
    if (threadIdx.x == 0 && blockIdx.x == 0) {
        const double N = (double)NPIX;
        double line_seg   = ws[0] / ws[2]  +  1.0 * (ws[1]  / (N - ws[2]));
        double junc_seg   = ws[3] / ws[5]  + 30.0 * (ws[4]  / (N - ws[5]));
        double sol_center = ws[6] / ws[8]  + 30.0 * (ws[7]  / (N - ws[8]));
        double tp_center  = ws[9] / ws[11] + 30.0 * (ws[10] / (N - ws[11]));
        double sol_disp   = ws[12] / ws[13];
        double tp_disp    = ws[14] / ws[15];
        double sol_len    = ws[16] / ws[18];
        double sol_angle  = ws[17] / ws[18];
        double tp_len     = ws[19] / ws[21];
        double tp_angle   = ws[20] / ws[21];
        double total = 10.0 * tp_center + tp_disp + tp_len + tp_angle +
                       sol_center + sol_disp + sol_len + sol_angle +
                       line_seg + junc_seg;
        out[0] = (float)total;
    }
}

extern "C" void kernel_launch(void* const* d_in, const int* in_sizes, int n_in,
                              void* d_out, int out_size, void* d_ws, size_t ws_size,
                              hipStream_t stream) {
    const float* preds = (const float*)d_in[0];
    const float* gts   = (const float*)d_in[1];
    double* ws = (double*)d_ws;

    // d_ws is re-poisoned to 0xAA before every launch — zero the accumulators.
    hipMemsetAsync(d_ws, 0, NACC * sizeof(double), stream);

    loss_kernel<<<GRID_BLOCKS, 256, 0, stream>>>(preds, gts, ws);
    finalize_kernel<<<1, 64, 0, stream>>>(ws, (float*)d_out);
}

// Round 7
// 279.256 us; speedup vs baseline: 1.0226x; 1.0226x over previous
//
#include <hip/hip_runtime.h>
#include <math.h>

// Problem geometry (fixed by the reference): B=32, C=16, H=W=256.
#define HW 65536
#define HW4 16384          // float4 groups per channel-plane
#define CTOT 16
#define BATCH 32
#define NPIX (BATCH * HW)  // 2,097,152 pixels per channel
#define NGRP (NPIX / 4)    // 524,288 float4 groups per channel

// Accumulator slots in workspace (double[22]) — see finalize_kernel.
#define NACC 22

// R4 structure (fastest so far): 2048 task-specialized blocks sweeping
// contiguous spans. R7 change: ALL global reads are NON-TEMPORAL so L3 does
// not allocate on miss -> no forced eviction/writeback of the harness
// restore's dirty Infinity-Cache lines during our window.
#define GRID_BLOCKS 2048

typedef float f32x4 __attribute__((ext_vector_type(4)));

__device__ __forceinline__ float4 ldnt(const float4* p) {
    f32x4 v = __builtin_nontemporal_load((const f32x4*)p);
    float4 r; r.x = v.x; r.y = v.y; r.z = v.z; r.w = v.w;
    return r;
}

__device__ __forceinline__ float smooth_l1(float p, float g) {
    float d = fabsf(p - g);
    return (d < 1.0f) ? 0.5f * d * d : d - 0.5f;
}
// a=|x| >= 0 so 1+exp(-a) in (1,2]: plain __logf is safe (abs err < 6e-8).
__device__ __forceinline__ float bce_logits(float x, float t) {
    float e = __expf(-fabsf(x));
    return fmaxf(x, 0.0f) - x * t + __logf(1.0f + e);
}
__device__ __forceinline__ float sigmoid_fast(float x) {
    return __builtin_amdgcn_rcpf(1.0f + __expf(-x));
}
__device__ __forceinline__ float get4(const float4& v, int j) {
    return j == 0 ? v.x : (j == 1 ? v.y : (j == 2 ? v.z : v.w));
}

__global__ __launch_bounds__(256) void loss_kernel(const float* __restrict__ preds,
                                                   const float* __restrict__ gts,
                                                   double* __restrict__ ws) {
    const float4* pf = (const float4*)preds;
    const float4* gf = (const float4*)gts;
    const int blk = blockIdx.x;
    const int tid = threadIdx.x;

    float acc0 = 0.0f, acc1 = 0.0f, acc2 = 0.0f;
    int base, nacc;

    if (blk < 512) {
        // ---------------- BCE task: 2 dense streams ----------------
        const int task = blk >> 7;                    // 0..3
        const int chs[4]   = {15, 14, 0, 7};
        const int bases[4] = {0, 3, 6, 9};
        const int ch = chs[task];
        base = bases[task];
        nacc = 3;
        const int lblk = blk & 127;
        const int start = lblk << 12;                 // span 4096 groups
        const int b = start >> 14;
        const int hw4s = start & (HW4 - 1);
        const size_t off = ((size_t)b * CTOT + ch) * HW4 + hw4s;
        const float4* pp = pf + off;
        const float4* gp = gf + off;
#pragma unroll 4
        for (int i = 0; i < 16; ++i) {
            const int o = (i << 8) + tid;
            float4 p = ldnt(pp + o);
            float4 t = ldnt(gp + o);
#pragma unroll
            for (int j = 0; j < 4; ++j) {
                float x  = get4(p, j);
                float tv = get4(t, j);
                float loss = bce_logits(x, tv);
                float pos  = (tv != 0.0f) ? 1.0f : 0.0f;
                acc0 += loss * pos;
                acc1 += loss * (1.0f - pos);
                acc2 += pos;
            }
        }
    } else if (blk < 1536) {
        // ---------------- displacement task: 8 dense streams ----------------
        const int task = (blk - 512) >> 9;            // 0..1
        const int c0 = task == 0 ? 1 : 8;
        base = task == 0 ? 12 : 14;
        nacc = 2;
        const int lblk = (blk - 512) & 511;
        const int start = lblk << 10;                 // span 1024 groups
        const int b = start >> 14;
        const int hw4s = start & (HW4 - 1);
        const size_t off = ((size_t)b * CTOT + c0) * HW4 + hw4s;
        const float4* pp = pf + off;
        const float4* gp = gf + off;
#pragma unroll 2
        for (int i = 0; i < 4; ++i) {
            const int o = (i << 8) + tid;
            float4 p0 = ldnt(pp + o + 0 * HW4);
            float4 p1 = ldnt(pp + o + 1 * HW4);
            float4 p2 = ldnt(pp + o + 2 * HW4);
            float4 p3 = ldnt(pp + o + 3 * HW4);
            float4 g0 = ldnt(gp + o + 0 * HW4);
            float4 g1 = ldnt(gp + o + 1 * HW4);
            float4 g2 = ldnt(gp + o + 2 * HW4);
            float4 g3 = ldnt(gp + o + 3 * HW4);
#pragma unroll
            for (int j = 0; j < 4; ++j) {
                float a0 = get4(p0, j), a1 = get4(p1, j), a2 = get4(p2, j), a3 = get4(p3, j);
                float b0 = get4(g0, j), b1 = get4(g1, j), b2 = get4(g2, j), b3 = get4(g3, j);
                float posv = fabsf(b0) + fabsf(b1) + fabsf(b2) + fabsf(b3);
                float m = (posv != 0.0f) ? 1.0f : 0.0f;
                float l1 = smooth_l1(a0, b0) + smooth_l1(a1, b1) +
                           smooth_l1(a2, b2) + smooth_l1(a3, b3);
                // swap = concat(pred[2:], pred[:2]) -> [p2,p3,p0,p1] vs gt
                float l2 = smooth_l1(a2, b0) + smooth_l1(a3, b1) +
                           smooth_l1(a0, b2) + smooth_l1(a1, b3);
                acc0 += fminf(l1, l2) * m;
                acc1 += m;
            }
        }
    } else {
        // ---------------- len/angle task: 4 dense streams ----------------
        const int task = (blk - 1536) >> 8;           // 0..1
        const int cl = task == 0 ? 5 : 12;
        base = task == 0 ? 16 : 19;
        nacc = 3;
        const int lblk = (blk - 1536) & 255;
        const int start = lblk << 11;                 // span 2048 groups
        const int b = start >> 14;
        const int hw4s = start & (HW4 - 1);
        const size_t off = ((size_t)b * CTOT + cl) * HW4 + hw4s;
        const float4* pp = pf + off;
        const float4* gp = gf + off;
#pragma unroll 2
        for (int i = 0; i < 8; ++i) {
            const int o = (i << 8) + tid;
            float4 pl = ldnt(pp + o + 0 * HW4);
            float4 pa = ldnt(pp + o + 1 * HW4);
            float4 gl = ldnt(gp + o + 0 * HW4);
            float4 ga = ldnt(gp + o + 1 * HW4);
#pragma unroll
            for (int j = 0; j < 4; ++j) {
                float glv = get4(gl, j);
                float m = (glv != 0.0f) ? 1.0f : 0.0f;
                acc0 += smooth_l1(sigmoid_fast(get4(pl, j)), glv) * m;
                acc1 += smooth_l1(sigmoid_fast(get4(pa, j)), get4(ga, j)) * m;
                acc2 += m;
            }
        }
    }

    // ---- wave (64-lane) butterfly reduce the (up to) 3 accumulators ----
#pragma unroll
    for (int off = 32; off > 0; off >>= 1) {
        acc0 += __shfl_down(acc0, off, 64);
        acc1 += __shfl_down(acc1, off, 64);
        acc2 += __shfl_down(acc2, off, 64);
    }

    __shared__ float red[4][3];
    const int lane = threadIdx.x & 63;
    const int wid  = threadIdx.x >> 6;
    if (lane == 0) { red[wid][0] = acc0; red[wid][1] = acc1; red[wid][2] = acc2; }
    __syncthreads();
    if (threadIdx.x == 0) {
        float s0 = red[0][0] + red[1][0] + red[2][0] + red[3][0];
        float s1 = red[0][1] + red[1][1] + red[2][1] + red[3][1];
        float s2 = red[0][2] + red[1][2] + red[2][2] + red[3][2];
        atomicAdd(&ws[base + 0], (double)s0);
        atomicAdd(&ws[base + 1], (double)s1);
        if (nacc == 3) atomicAdd(&ws[base + 2], (double)s2);
    }
}

__global__ void finalize_kernel(const double* __restrict__ ws, float* __restrict__ out) {
    if (threadIdx.x == 0 && blockIdx.x == 0) {
        const double N = (double)NPIX;
        double line_seg   = ws[0] / ws[2]  +  1.0 * (ws[1]  / (N - ws[2]));
        double junc_seg   = ws[3] / ws[5]  + 30.0 * (ws[4]  / (N - ws[5]));
        double sol_center = ws[6] / ws[8]  + 30.0 * (ws[7]  / (N - ws[8]));
        double tp_center  = ws[9] / ws[11] + 30.0 * (ws[10] / (N - ws[11]));
        double sol_disp   = ws[12] / ws[13];
        double tp_disp    = ws[14] / ws[15];
        double sol_len    = ws[16] / ws[18];
        double sol_angle  = ws[17] / ws[18];
        double tp_len     = ws[19] / ws[21];
        double tp_angle   = ws[20] / ws[21];
        double total = 10.0 * tp_center + tp_disp + tp_len + tp_angle +
                       sol_center + sol_disp + sol_len + sol_angle +
                       line_seg + junc_seg;
        out[0] = (float)total;
    }
}

extern "C" void kernel_launch(void* const* d_in, const int* in_sizes, int n_in,
                              void* d_out, int out_size, void* d_ws, size_t ws_size,
                              hipStream_t stream) {
    const float* preds = (const float*)d_in[0];
    const float* gts   = (const float*)d_in[1];
    double* ws = (double*)d_ws;

    // d_ws is re-poisoned to 0xAA before every launch — zero the accumulators.
    hipMemsetAsync(d_ws, 0, NACC * sizeof(double), stream);

    loss_kernel<<<GRID_BLOCKS, 256, 0, stream>>>(preds, gts, ws);
    finalize_kernel<<<1, 64, 0, stream>>>(ws, (float*)d_out);
}